// Round 2
// baseline (8514.954 us; speedup 1.0000x reference)
//
#include <hip/hip_runtime.h>
#include <hip/hip_bf16.h>

#define NB 512
#define NT 256
#define NL 15
#define POS 100
#define NCOL 101
#define EPS 1e-6f

// ---- output offsets (floats) ----
#define O_H    0
#define O_KS   2048
#define SZ_KS  (13*512*256)
#define O_VS   (O_KS + SZ_KS)
#define O_KF   (O_VS + SZ_KS)
#define SZ_KF  (2*1024*256)
#define O_VF   (O_KF + SZ_KF)
#define O_PLE  (O_VF + SZ_KF)
#define O_K13  (O_PLE + 30*256)
#define O_V13  (O_K13 + 512*256)
#define O_K14  (O_V13 + 512*256)
#define O_V14  (O_K14 + 1024*256)

struct P {
    const float *hidden, *raw;
    const float *cos_s, *sin_s, *cos_f, *sin_f;
    const float *Ksl, *Vsl, *Kfl, *Vfl;
    const float *ple_conv_w, *ple_norm_w, *W_ple;
    const float *Wq, *Wk, *Wv, *Wo;
    const float *w_in, *w_post, *w_qn, *w_kn;
    const float *Wg, *Wu, *Wd;
    float *out, *pleb;
    float *qkv_all, *gu_all, *ctx, *proj, *kall, *vall;
    int *bar_cnt, *bar_gen;
};

__device__ __forceinline__ float geluf(float x) {
    float x3 = x*x*x;
    return 0.5f*x*(1.f + tanhf(0.7978845608028654f*(x + 0.044715f*x3)));
}

__device__ __forceinline__ float brsum256(float v, float* sred) {
    #pragma unroll
    for (int o=32;o>0;o>>=1) v += __shfl_xor(v,o);
    __syncthreads();
    if ((threadIdx.x&63)==0) sred[threadIdx.x>>6]=v;
    __syncthreads();
    return sred[0]+sred[1]+sred[2]+sred[3];
}
__device__ __forceinline__ float brmax256(float v, float* sred) {
    #pragma unroll
    for (int o=32;o>0;o>>=1) v = fmaxf(v,__shfl_xor(v,o));
    __syncthreads();
    if ((threadIdx.x&63)==0) sred[threadIdx.x>>6]=v;
    __syncthreads();
    return fmaxf(fmaxf(sred[0],sred[1]),fmaxf(sred[2],sred[3]));
}

// grid barrier: agent-scope release/acquire (cross-XCD coherent)
__device__ __forceinline__ void gridbar(int* cnt, int* gen) {
    __syncthreads();
    if (threadIdx.x == 0) {
        int g = __hip_atomic_load(gen, __ATOMIC_RELAXED, __HIP_MEMORY_SCOPE_AGENT);
        int n = __hip_atomic_fetch_add(cnt, 1, __ATOMIC_ACQ_REL, __HIP_MEMORY_SCOPE_AGENT);
        if (n == NB-1) {
            __hip_atomic_store(cnt, 0, __ATOMIC_RELAXED, __HIP_MEMORY_SCOPE_AGENT);
            __hip_atomic_fetch_add(gen, 1, __ATOMIC_ACQ_REL, __HIP_MEMORY_SCOPE_AGENT);
        } else {
            while (__hip_atomic_load(gen, __ATOMIC_ACQUIRE, __HIP_MEMORY_SCOPE_AGENT) == g)
                __builtin_amdgcn_s_sleep(2);
        }
    }
    __syncthreads();
}

// generic gemv column tile: Wt pre-offset to (i0, col0); outt pre-offset to col0.
// MODE 0: x = rms(src0)*(1+src1); 1: gelu(src0)*src1; 2: gelu(src0); 3: raw
template<int MODE>
__device__ void gemv_tile(const float* __restrict__ Wt, int Nld, int nact,
        int i0, int R, int K,
        const float* __restrict__ src0, const float* __restrict__ src1,
        float* __restrict__ outt, float* smem)
{
    int t = threadIdx.x;
    float rs = 1.f;
    if (MODE == 0) {
        float ss = 0.f;
        for (int i=t;i<K;i+=NT){ float v=src0[i]; ss += v*v; }
        ss = brsum256(ss, smem);
        rs = rsqrtf(ss/(float)K + EPS);
    }
    float* xs = smem + 8;
    for (int i=t;i<R;i+=NT){
        int ii = i0+i; float x;
        if (MODE==0)      x = src0[ii]*rs*(1.f+src1[ii]);
        else if (MODE==1) x = geluf(src0[ii])*src1[ii];
        else if (MODE==2) x = geluf(src0[ii]);
        else              x = src0[ii];
        xs[i] = x;
    }
    __syncthreads();
    if (t < nact) {
        const float* base = Wt + t*4;
        float4 acc = make_float4(0.f,0.f,0.f,0.f);
        #pragma unroll 4
        for (int r=0;r<R;r++){
            float4 w = *reinterpret_cast<const float4*>(base + (size_t)r*Nld);
            float x = xs[r];
            acc.x += x*w.x; acc.y += x*w.y; acc.z += x*w.z; acc.w += x*w.w;
        }
        atomicAdd(outt+t*4+0, acc.x);
        atomicAdd(outt+t*4+1, acc.y);
        atomicAdd(outt+t*4+2, acc.z);
        atomicAdd(outt+t*4+3, acc.w);
    }
    __syncthreads();
}

// jq phase tiles: 0..255 Wq (2 col-tiles x 128 chunks R=16); 256..287 Wk (R=64); 288..319 Wv
__device__ void jq_tile(const P& p, int l, const float* hsrc, int task, float* smem) {
    float* qkv = p.qkv_all + l*2560;
    const float* w1 = p.w_in + l*2048;
    if (task < 256) {
        int cb = task&1, kc = task>>1, i0 = kc*16;
        gemv_tile<0>(p.Wq + (size_t)l*2048*2048 + (size_t)i0*2048 + cb*1024,
                     2048, 256, i0, 16, 2048, hsrc, w1, qkv + cb*1024, smem);
    } else if (task < 288) {
        int kc = task-256, i0 = kc*64;
        gemv_tile<0>(p.Wk + (size_t)l*2048*256 + (size_t)i0*256,
                     256, 64, i0, 64, 2048, hsrc, w1, qkv + 2048, smem);
    } else {
        int kc = task-288, i0 = kc*64;
        gemv_tile<0>(p.Wv + (size_t)l*2048*256 + (size_t)i0*256,
                     256, 64, i0, 64, 2048, hsrc, w1, qkv + 2304, smem);
    }
}

__device__ void ple_fin_task(const P& p, int g, float* smem) {
    int t = threadIdx.x;
    float v = p.proj[g*256+t];
    float ss = brsum256(v*v, smem);
    float rms = rsqrtf(ss*(1.f/256.f) + EPS);
    p.pleb[g*256+t] = (v*rms*p.ple_norm_w[t] + p.raw[g*256+t]) * 0.7071067811865476f;
    __syncthreads();
}

__device__ void attn_task(const P& p, int l, int head, int full, float* smem) {
    float* sred = smem; float* qs = smem+8; float* ksh = smem+264; float* sc = smem+520;
    int t = threadIdx.x;
    const float* qkv = p.qkv_all + l*2560;
    const float* cosv = full ? p.cos_f : p.cos_s;
    const float* sinv = full ? p.sin_f : p.sin_s;
    int fi = (l==14) ? 1 : 0;
    int si = l - (l>4 ? 1 : 0);
    const float* Kin = full ? p.Kfl + (size_t)fi*1024*256 : p.Ksl + (size_t)si*512*256;
    const float* Vin = full ? p.Vfl + (size_t)fi*1024*256 : p.Vsl + (size_t)si*512*256;
    const float* wqn = p.w_qn + l*256; const float* wkn = p.w_kn + l*256;

    float qv = qkv[head*256+t];
    float ss = brsum256(qv*qv, sred);
    float qn = qv * rsqrtf(ss*(1.f/256.f)+EPS) * (1.f+wqn[t]);
    qs[t]=qn; __syncthreads();
    float qr = qn*cosv[t] + ((t<128)? -qs[t+128] : qs[t-128])*sinv[t];
    __syncthreads(); qs[t]=qr;
    float kv = qkv[2048+t];
    float ks2 = brsum256(kv*kv, sred);
    float kn = kv*rsqrtf(ks2*(1.f/256.f)+EPS)*(1.f+wkn[t]);
    ksh[t]=kn; __syncthreads();
    float kr = kn*cosv[t] + ((t<128)? -ksh[t+128] : ksh[t-128])*sinv[t];
    __syncthreads(); ksh[t]=kr;
    if (head==0){ p.kall[l*256+t]=kr; p.vall[l*256+t]=qkv[2304+t]; }
    __syncthreads();

    float score = -1e30f;
    if (t < NCOL) {
        float acc = 0.f;
        if (t == POS) {
            for (int d=0; d<256; d++) acc += qs[d]*ksh[d];
        } else {
            const float4* kr4 = reinterpret_cast<const float4*>(Kin + (size_t)t*256);
            #pragma unroll 8
            for (int d4=0; d4<64; d4++){
                float4 k4 = kr4[d4];
                acc += qs[d4*4]*k4.x + qs[d4*4+1]*k4.y + qs[d4*4+2]*k4.z + qs[d4*4+3]*k4.w;
            }
        }
        score = acc * 0.0625f;
    }
    float mx = brmax256(score, sred);
    float e = (t<NCOL) ? expf(score-mx) : 0.f;
    float s = brsum256(e, sred);
    if (t < 128) sc[t] = (t<NCOL) ? e/s : 0.f;
    __syncthreads();
    float acc = 0.f;
    for (int c=0; c<POS; c++) acc += sc[c]*Vin[(size_t)c*256+t];
    acc += sc[POS]*qkv[2304+t];
    p.ctx[head*256+t] = acc;
    __syncthreads();
}

// row mapping for KV cache copy; returns false for patch rows (r==POS)
__device__ bool kv_row(const P& p, int row, const float*& src, float*& dst) {
    if (row < 6656) {
        int r = row&511; dst = p.out + O_KS + (size_t)row*256;
        if (r==POS) return false; src = p.Ksl + (size_t)row*256;
    } else if (row < 13312) {
        int idx = row-6656; int r = idx&511; dst = p.out + O_VS + (size_t)idx*256;
        if (r==POS) return false; src = p.Vsl + (size_t)idx*256;
    } else if (row < 15360) {
        int idx = row-13312; int r = idx&1023; dst = p.out + O_KF + (size_t)idx*256;
        if (r==POS) return false; src = p.Kfl + (size_t)idx*256;
    } else if (row < 17408) {
        int idx = row-15360; int r = idx&1023; dst = p.out + O_VF + (size_t)idx*256;
        if (r==POS) return false; src = p.Vfl + (size_t)idx*256;
    } else if (row < 17920) {
        int r = row-17408; dst = p.out + O_K13 + (size_t)r*256;
        if (r==POS) return false; src = p.Ksl + (size_t)(12*512+r)*256;
    } else if (row < 18432) {
        int r = row-17920; dst = p.out + O_V13 + (size_t)r*256;
        if (r==POS) return false; src = p.Vsl + (size_t)(12*512+r)*256;
    } else if (row < 19456) {
        int r = row-18432; dst = p.out + O_K14 + (size_t)r*256;
        if (r==POS) return false; src = p.Kfl + (size_t)(1024+r)*256;
    } else {
        int r = row-19456; dst = p.out + O_V14 + (size_t)r*256;
        if (r==POS) return false; src = p.Vfl + (size_t)(1024+r)*256;
    }
    return true;
}

__device__ __forceinline__ int slay(int s) { return s + (s>=4 ? 1 : 0); }

__device__ void patch_task(const P& p, int i) {
    int t = threadIdx.x;
    const float* src; float* dst;
    if (i < 13)      { dst = p.out + O_KS + ((size_t)i*512+POS)*256;        src = p.kall + slay(i)*256; }
    else if (i < 26) { int s=i-13; dst = p.out + O_VS + ((size_t)s*512+POS)*256; src = p.vall + slay(s)*256; }
    else if (i==26)  { dst = p.out + O_KF + (size_t)POS*256;                src = p.kall + 4*256; }
    else if (i==27)  { dst = p.out + O_KF + (size_t)(1024+POS)*256;         src = p.kall + 14*256; }
    else if (i==28)  { dst = p.out + O_VF + (size_t)POS*256;                src = p.vall + 4*256; }
    else if (i==29)  { dst = p.out + O_VF + (size_t)(1024+POS)*256;         src = p.vall + 14*256; }
    else if (i==30)  { dst = p.out + O_K13 + (size_t)POS*256;               src = p.kall + 13*256; }
    else if (i==31)  { dst = p.out + O_V13 + (size_t)POS*256;               src = p.vall + 13*256; }
    else if (i==32)  { dst = p.out + O_K14 + (size_t)POS*256;               src = p.kall + 14*256; }
    else             { dst = p.out + O_V14 + (size_t)POS*256;               src = p.vall + 14*256; }
    dst[t] = src[t];
}

__global__ __launch_bounds__(NT, 2) void mega(P p) {
    __shared__ float smem[8+256+256+128];
    int bid = blockIdx.x, t = threadIdx.x;
    float* hbuf = p.out + O_H;

    // Pz: zero accumulators, copy hidden -> h
    for (int i = bid*NT+t; i < 161280; i += NB*NT) p.qkv_all[i] = 0.f;
    if (bid == NB-1) for (int i=t; i<2048; i+=NT) hbuf[i] = p.hidden[i];
    gridbar(p.bar_cnt, p.bar_gen);

    // P0: jq(layer 0) + ple_conv  (320 + 1920 tasks)
    for (int task = bid; task < 2240; task += NB) {
        if (task < 320) jq_tile(p, 0, p.hidden, task, smem);
        else {
            int g = task-320; int wid = t>>6, lane = t&63;
            int row = g*4 + wid;
            const float4* wr = reinterpret_cast<const float4*>(p.ple_conv_w + (size_t)row*2048);
            const float4* hr = reinterpret_cast<const float4*>(p.hidden);
            float acc = 0.f;
            #pragma unroll
            for (int it=0; it<8; it++){
                float4 w = wr[it*64+lane], x = hr[it*64+lane];
                acc += w.x*x.x + w.y*x.y + w.z*x.z + w.w*x.w;
            }
            #pragma unroll
            for (int o=32;o>0;o>>=1) acc += __shfl_xor(acc,o);
            if (lane==0) p.proj[row] = acc * 0.022097086912079608f;
        }
    }
    gridbar(p.bar_cnt, p.bar_gen);

    for (int l=0; l<NL; l++) {
        int full = (l==4 || l==14);
        // PA: attention (8) + ple_fin (30, l==0 only) + KV copy slice (86)
        for (int task = bid; task < 124; task += NB) {
            if (task < 8) attn_task(p, l, task, full, smem);
            else if (task < 38) { if (l==0) ple_fin_task(p, task-8, smem); }
            else {
                int kvt = l*86 + (task-38);
                for (int rr=0; rr<16; rr++) {
                    int row = kvt*16 + rr;
                    if (row < 20480) {
                        const float* s; float* d;
                        if (kv_row(p, row, s, d)) d[t] = s[t];
                    }
                }
            }
        }
        gridbar(p.bar_cnt, p.bar_gen);

        // PB: o-proj (256 tiles, R=16)
        for (int task = bid; task < 256; task += NB) {
            int cb = task&1, kc = task>>1, i0 = kc*16;
            gemv_tile<3>(p.Wo + (size_t)l*2048*2048 + (size_t)i0*2048 + cb*1024,
                         2048, 256, i0, 16, 2048, p.ctx, nullptr, hbuf + cb*1024, smem);
        }
        gridbar(p.bar_cnt, p.bar_gen);

        // PC: gate/up (512 tiles, R=32)
        for (int task = bid; task < 512; task += NB) {
            int cb = task&7, kc = task>>3, i0 = kc*32;
            const float* Wm = (cb<4 ? p.Wg : p.Wu) + (size_t)l*2048*4096 + (size_t)i0*4096 + (cb&3)*1024;
            float* ot = p.gu_all + l*8192 + (cb<4 ? 0 : 4096) + (cb&3)*1024;
            gemv_tile<0>(Wm, 4096, 256, i0, 32, 2048, hbuf, p.w_post + l*2048, ot, smem);
        }
        gridbar(p.bar_cnt, p.bar_gen);

        // PD: down-proj (256 tiles) + ple-proj (16 tiles)
        for (int task = bid; task < 272; task += NB) {
            if (task < 16) {
                int cb = task&1, kc = task>>1, i0 = kc*32;
                gemv_tile<2>(p.W_ple + (size_t)l*256*2048 + (size_t)i0*2048 + cb*1024,
                             2048, 256, i0, 32, 256, p.pleb + l*256, nullptr, hbuf + cb*1024, smem);
            } else {
                int tt = task-16, cb = tt&1, kc = tt>>1, i0 = kc*32;
                gemv_tile<1>(p.Wd + (size_t)l*4096*2048 + (size_t)i0*2048 + cb*1024,
                             2048, 256, i0, 32, 4096,
                             p.gu_all + l*8192, p.gu_all + l*8192 + 4096, hbuf + cb*1024, smem);
            }
        }
        gridbar(p.bar_cnt, p.bar_gen);

        // PE: qkv for next layer
        if (l < 14) {
            for (int task = bid; task < 320; task += NB) jq_tile(p, l+1, hbuf, task, smem);
            gridbar(p.bar_cnt, p.bar_gen);
        }
    }

    // PF: KV patch rows (row POS of every cache region)
    for (int task = bid; task < 34; task += NB) patch_task(p, task);
}

extern "C" void kernel_launch(void* const* d_in, const int* in_sizes, int n_in,
                              void* d_out, int out_size, void* d_ws, size_t ws_size,
                              hipStream_t stream) {
    float* ws = (float*)d_ws;
    P p;
    p.hidden = (const float*)d_in[0];
    p.raw    = (const float*)d_in[4];
    p.cos_s  = (const float*)d_in[5];
    p.sin_s  = (const float*)d_in[6];
    p.cos_f  = (const float*)d_in[7];
    p.sin_f  = (const float*)d_in[8];
    p.Ksl    = (const float*)d_in[9];
    p.Vsl    = (const float*)d_in[10];
    p.Kfl    = (const float*)d_in[11];
    p.Vfl    = (const float*)d_in[12];
    p.ple_conv_w = (const float*)d_in[13];
    p.ple_norm_w = (const float*)d_in[14];
    p.W_ple  = (const float*)d_in[15];
    p.Wq     = (const float*)d_in[16];
    p.Wk     = (const float*)d_in[17];
    p.Wv     = (const float*)d_in[18];
    p.Wo     = (const float*)d_in[19];
    p.w_in   = (const float*)d_in[20];
    p.w_post = (const float*)d_in[21];
    p.w_qn   = (const float*)d_in[22];
    p.w_kn   = (const float*)d_in[23];
    p.Wg     = (const float*)d_in[24];
    p.Wu     = (const float*)d_in[25];
    p.Wd     = (const float*)d_in[26];
    p.out    = (float*)d_out;
    p.pleb   = p.out + O_PLE;
    p.qkv_all = ws;            // 15*2560
    p.gu_all  = ws + 38400;    // 15*8192  (contiguous accum region: 161280 floats)
    p.ctx     = ws + 161280;   // 2048
    p.proj    = ws + 163328;   // 7680
    p.kall    = ws + 171008;   // 15*256
    p.vall    = ws + 174848;   // 15*256
    p.bar_cnt = (int*)(ws + 178688);
    p.bar_gen = p.bar_cnt + 1;

    hipMemsetAsync(ws + 178688, 0, 8, stream);
    void* args[] = { &p };
    hipLaunchCooperativeKernel(reinterpret_cast<void*>(mega), dim3(NB), dim3(NT),
                               args, 0, stream);
}

// Round 5
// 3738.829 us; speedup vs baseline: 2.2774x; 2.2774x over previous
//
#include <hip/hip_runtime.h>
#include <hip/hip_bf16.h>

#define NBMAX 512
#define NT 256
#define NL 15
#define POS 100
#define NCOL 101
#define EPS 1e-6f

// ---- output offsets (floats) ----
#define O_H    0
#define O_KS   2048
#define SZ_KS  (13*512*256)
#define O_VS   (O_KS + SZ_KS)
#define O_KF   (O_VS + SZ_KS)
#define SZ_KF  (2*1024*256)
#define O_VF   (O_KF + SZ_KF)
#define O_PLE  (O_VF + SZ_KF)
#define O_K13  (O_PLE + 30*256)
#define O_V13  (O_K13 + 512*256)
#define O_K14  (O_V13 + 512*256)
#define O_V14  (O_K14 + 1024*256)

struct P {
    const float *hidden, *raw;
    const float *cos_s, *sin_s, *cos_f, *sin_f;
    const float *Ksl, *Vsl, *Kfl, *Vfl;
    const float *ple_conv_w, *ple_norm_w, *W_ple;
    const float *Wq, *Wk, *Wv, *Wo;
    const float *w_in, *w_post, *w_qn, *w_kn;
    const float *Wg, *Wu, *Wd;
    float *out, *pleb;
    float *qkv_all, *gu_all, *pleh, *ctx, *proj, *kall, *vall;
    int *bars;
};

__device__ __forceinline__ float geluf(float x) {
    float x3 = x*x*x;
    return 0.5f*x*(1.f + tanhf(0.7978845608028654f*(x + 0.044715f*x3)));
}

__device__ __forceinline__ float brsum256(float v, float* sred) {
    #pragma unroll
    for (int o=32;o>0;o>>=1) v += __shfl_xor(v,o);
    __syncthreads();
    if ((threadIdx.x&63)==0) sred[threadIdx.x>>6]=v;
    __syncthreads();
    return sred[0]+sred[1]+sred[2]+sred[3];
}
__device__ __forceinline__ float brmax256(float v, float* sred) {
    #pragma unroll
    for (int o=32;o>0;o>>=1) v = fmaxf(v,__shfl_xor(v,o));
    __syncthreads();
    if ((threadIdx.x&63)==0) sred[threadIdx.x>>6]=v;
    __syncthreads();
    return fmaxf(fmaxf(sred[0],sred[1]),fmaxf(sred[2],sred[3]));
}

// Hierarchical grid barrier (grid size = gridDim.x, multiple of 8).
// ACQ_REL RMW per block on its slot counter, RELAXED polls with sleep
// backoff, ONE ACQUIRE load per block on exit.
__device__ __forceinline__ void gridbar(int* bars) {
    __syncthreads();
    if (threadIdx.x == 0) {
        int slot = blockIdx.x & 7;
        int target = ((int)gridDim.x >> 3) - 1;
        int* cnt    = bars + slot*64;
        int* master = bars + 8*64;
        int* gslot  = bars + (9+slot)*64;
        int g = __hip_atomic_load(gslot, __ATOMIC_RELAXED, __HIP_MEMORY_SCOPE_AGENT);
        int n = __hip_atomic_fetch_add(cnt, 1, __ATOMIC_ACQ_REL, __HIP_MEMORY_SCOPE_AGENT);
        if (n == target) {
            __hip_atomic_store(cnt, 0, __ATOMIC_RELAXED, __HIP_MEMORY_SCOPE_AGENT);
            int m = __hip_atomic_fetch_add(master, 1, __ATOMIC_ACQ_REL, __HIP_MEMORY_SCOPE_AGENT);
            if (m == 7) {
                __hip_atomic_store(master, 0, __ATOMIC_RELAXED, __HIP_MEMORY_SCOPE_AGENT);
                #pragma unroll
                for (int s=0;s<8;s++)
                    __hip_atomic_fetch_add(bars + (9+s)*64, 1, __ATOMIC_RELEASE, __HIP_MEMORY_SCOPE_AGENT);
            }
        }
        while (__hip_atomic_load(gslot, __ATOMIC_RELAXED, __HIP_MEMORY_SCOPE_AGENT) == g)
            __builtin_amdgcn_s_sleep(8);
        int gg = __hip_atomic_load(gslot, __ATOMIC_ACQUIRE, __HIP_MEMORY_SCOPE_AGENT);
        asm volatile("" :: "v"(gg) : "memory");
    }
    __syncthreads();
}

// one wave computes a [R rows x 256 cols] tile: lane covers cols 4l..4l+3
// MODE 0: x=rms(src0)*(1+src1); 1: gelu(src0)*src1; 2: gelu(src0); 3: raw
template<int MODE, int R>
__device__ __forceinline__ void gemv_wave(const float* __restrict__ Wt, int N,
        int i0, int K,
        const float* __restrict__ src0, const float* __restrict__ src1,
        float* __restrict__ outc)
{
    int lane = threadIdx.x & 63;
    float rs = 1.f;
    if (MODE == 0) {
        const float4* s4 = reinterpret_cast<const float4*>(src0);
        float ss = 0.f;
        for (int i=lane; i<K/4; i+=64){ float4 v=s4[i]; ss += v.x*v.x+v.y*v.y+v.z*v.z+v.w*v.w; }
        #pragma unroll
        for (int o=32;o>0;o>>=1) ss += __shfl_xor(ss,o);
        rs = rsqrtf(ss/(float)K + EPS);
    }
    float4 acc = make_float4(0.f,0.f,0.f,0.f);
    #pragma unroll 4
    for (int r=0;r<R;r++){
        int ii = i0+r; float x;
        if (MODE==0)      x = src0[ii]*rs*(1.f+src1[ii]);
        else if (MODE==1) x = geluf(src0[ii])*src1[ii];
        else if (MODE==2) x = geluf(src0[ii]);
        else              x = src0[ii];
        float4 w = reinterpret_cast<const float4*>(Wt + (size_t)r*N)[lane];
        acc.x += x*w.x; acc.y += x*w.y; acc.z += x*w.z; acc.w += x*w.w;
    }
    atomicAdd(outc+lane*4+0, acc.x);
    atomicAdd(outc+lane*4+1, acc.y);
    atomicAdd(outc+lane*4+2, acc.z);
    atomicAdd(outc+lane*4+3, acc.w);
}

__device__ void jq_task(const P& p, int l, const float* hs, int task) {
    float* qkv = p.qkv_all + l*2560;
    const float* w1 = p.w_in + (size_t)l*2048;
    if (task < 1024) {
        int strip=task&7, kc=task>>3, i0=kc*16, c0=strip*256;
        gemv_wave<0,16>(p.Wq + (size_t)l*2048*2048 + (size_t)i0*2048 + c0, 2048,
                        i0, 2048, hs, w1, qkv + c0);
    } else if (task < 1152) {
        int kc=task-1024, i0=kc*16;
        gemv_wave<0,16>(p.Wk + (size_t)l*2048*256 + (size_t)i0*256, 256,
                        i0, 2048, hs, w1, qkv + 2048);
    } else {
        int kc=task-1152, i0=kc*16;
        gemv_wave<0,16>(p.Wv + (size_t)l*2048*256 + (size_t)i0*256, 256,
                        i0, 2048, hs, w1, qkv + 2304);
    }
}

__device__ void ple_fin_task(const P& p, int g, float* smem) {
    int t = threadIdx.x;
    float v = p.proj[g*256+t];
    float ss = brsum256(v*v, smem);
    float rms = rsqrtf(ss*(1.f/256.f) + EPS);
    p.pleb[g*256+t] = (v*rms*p.ple_norm_w[t] + p.raw[g*256+t]) * 0.7071067811865476f;
}

__device__ void attn_task(const P& p, int l, int head, int full, float* smem) {
    float* sred = smem; float* qs = smem+8; float* ksh = smem+264; float* sc = smem+520;
    int t = threadIdx.x;
    const float* qkv = p.qkv_all + l*2560;
    const float* cosv = full ? p.cos_f : p.cos_s;
    const float* sinv = full ? p.sin_f : p.sin_s;
    int fi = (l==14) ? 1 : 0;
    int si = l - (l>4 ? 1 : 0);
    const float* Kin = full ? p.Kfl + (size_t)fi*1024*256 : p.Ksl + (size_t)si*512*256;
    const float* Vin = full ? p.Vfl + (size_t)fi*1024*256 : p.Vsl + (size_t)si*512*256;
    const float* wqn = p.w_qn + l*256; const float* wkn = p.w_kn + l*256;

    float qv = qkv[head*256+t];
    float ss = brsum256(qv*qv, sred);
    float qn = qv * rsqrtf(ss*(1.f/256.f)+EPS) * (1.f+wqn[t]);
    qs[t]=qn; __syncthreads();
    float qr = qn*cosv[t] + ((t<128)? -qs[t+128] : qs[t-128])*sinv[t];
    __syncthreads(); qs[t]=qr;
    float kv = qkv[2048+t];
    float ks2 = brsum256(kv*kv, sred);
    float kn = kv*rsqrtf(ks2*(1.f/256.f)+EPS)*(1.f+wkn[t]);
    ksh[t]=kn; __syncthreads();
    float kr = kn*cosv[t] + ((t<128)? -ksh[t+128] : ksh[t-128])*sinv[t];
    __syncthreads(); ksh[t]=kr;
    if (head==0){ p.kall[l*256+t]=kr; p.vall[l*256+t]=qkv[2304+t]; }
    __syncthreads();

    float score = -1e30f;
    if (t < NCOL) {
        float acc = 0.f;
        if (t == POS) {
            for (int d=0; d<256; d++) acc += qs[d]*ksh[d];
        } else {
            const float4* kr4 = reinterpret_cast<const float4*>(Kin + (size_t)t*256);
            #pragma unroll 8
            for (int d4=0; d4<64; d4++){
                float4 k4 = kr4[d4];
                acc += qs[d4*4]*k4.x + qs[d4*4+1]*k4.y + qs[d4*4+2]*k4.z + qs[d4*4+3]*k4.w;
            }
        }
        score = acc * 0.0625f;
    }
    float mx = brmax256(score, sred);
    float e = (t<NCOL) ? expf(score-mx) : 0.f;
    float s = brsum256(e, sred);
    if (t < 128) sc[t] = (t<NCOL) ? e/s : 0.f;
    __syncthreads();
    float acc = 0.f;
    for (int c=0; c<POS; c++) acc += sc[c]*Vin[(size_t)c*256+t];
    acc += sc[POS]*qkv[2304+t];
    p.ctx[head*256+t] = acc;
}

__device__ bool kv_row(const P& p, int row, const float*& src, float*& dst) {
    if (row < 6656) {
        int r = row&511; dst = p.out + O_KS + (size_t)row*256;
        if (r==POS) return false; src = p.Ksl + (size_t)row*256;
    } else if (row < 13312) {
        int idx = row-6656; int r = idx&511; dst = p.out + O_VS + (size_t)idx*256;
        if (r==POS) return false; src = p.Vsl + (size_t)idx*256;
    } else if (row < 15360) {
        int idx = row-13312; int r = idx&1023; dst = p.out + O_KF + (size_t)idx*256;
        if (r==POS) return false; src = p.Kfl + (size_t)idx*256;
    } else if (row < 17408) {
        int idx = row-15360; int r = idx&1023; dst = p.out + O_VF + (size_t)idx*256;
        if (r==POS) return false; src = p.Vfl + (size_t)idx*256;
    } else if (row < 17920) {
        int r = row-17408; dst = p.out + O_K13 + (size_t)r*256;
        if (r==POS) return false; src = p.Ksl + (size_t)(12*512+r)*256;
    } else if (row < 18432) {
        int r = row-17920; dst = p.out + O_V13 + (size_t)r*256;
        if (r==POS) return false; src = p.Vsl + (size_t)(12*512+r)*256;
    } else if (row < 19456) {
        int r = row-18432; dst = p.out + O_K14 + (size_t)r*256;
        if (r==POS) return false; src = p.Kfl + (size_t)(1024+r)*256;
    } else {
        int r = row-19456; dst = p.out + O_V14 + (size_t)r*256;
        if (r==POS) return false; src = p.Vfl + (size_t)(1024+r)*256;
    }
    return true;
}

__device__ __forceinline__ int slay(int s) { return s + (s>=4 ? 1 : 0); }

__device__ void patch_row(const P& p, int i, int lane) {
    const float* src; float* dst;
    if (i < 13)      { dst = p.out + O_KS + ((size_t)i*512+POS)*256;        src = p.kall + slay(i)*256; }
    else if (i < 26) { int s=i-13; dst = p.out + O_VS + ((size_t)s*512+POS)*256; src = p.vall + slay(s)*256; }
    else if (i==26)  { dst = p.out + O_KF + (size_t)POS*256;                src = p.kall + 4*256; }
    else if (i==27)  { dst = p.out + O_KF + (size_t)(1024+POS)*256;         src = p.kall + 14*256; }
    else if (i==28)  { dst = p.out + O_VF + (size_t)POS*256;                src = p.vall + 4*256; }
    else if (i==29)  { dst = p.out + O_VF + (size_t)(1024+POS)*256;         src = p.vall + 14*256; }
    else if (i==30)  { dst = p.out + O_K13 + (size_t)POS*256;               src = p.kall + 13*256; }
    else if (i==31)  { dst = p.out + O_V13 + (size_t)POS*256;               src = p.vall + 13*256; }
    else if (i==32)  { dst = p.out + O_K14 + (size_t)POS*256;               src = p.kall + 14*256; }
    else             { dst = p.out + O_V14 + (size_t)POS*256;               src = p.vall + 14*256; }
    reinterpret_cast<float4*>(dst)[lane] = reinterpret_cast<const float4*>(src)[lane];
}

__global__ __launch_bounds__(NT, 4) void mega(P p) {
    __shared__ float smem[648];
    int bid = blockIdx.x, t = threadIdx.x;
    int wid = t>>6, lane = t&63;
    int gw = bid*4 + wid;
    int NW = (int)gridDim.x * 4;
    float* hbuf = p.out + O_H;

    // Pz: zero accumulators (qkv_all | gu_all | pleh = 192000 floats), copy h
    {
        float4* z4 = reinterpret_cast<float4*>(p.qkv_all);
        for (int i=bid*NT+t; i<48000; i+=(int)gridDim.x*NT) z4[i]=make_float4(0.f,0.f,0.f,0.f);
        if (bid==0) for (int i=t;i<2048;i+=NT) hbuf[i]=p.hidden[i];
    }
    gridbar(p.bars);

    // P0: jq(layer0 from hidden) 1280 + ple_conv 1920 wave-tasks (x4 rows = 7680)
    for (int task=gw; task<3200; task+=NW){
        if (task<1280) jq_task(p, 0, p.hidden, task);
        else {
            int t4 = (task-1280)*4;
            for (int rr=0; rr<4; rr++){
                int row = t4+rr;
                const float4* wr = reinterpret_cast<const float4*>(p.ple_conv_w + (size_t)row*2048);
                const float4* hr = reinterpret_cast<const float4*>(p.hidden);
                float acc = 0.f;
                #pragma unroll
                for (int it=0; it<8; it++){
                    int idx = it*64+lane;
                    float4 w = wr[idx], x = hr[idx];
                    acc += w.x*x.x + w.y*x.y + w.z*x.z + w.w*x.w;
                }
                #pragma unroll
                for (int o=32;o>0;o>>=1) acc += __shfl_xor(acc,o);
                if (lane==0) p.proj[row] = acc * 0.022097086912079608f;
            }
        }
    }
    gridbar(p.bars);

    for (int l=0; l<NL; l++) {
        int full = (l==4 || l==14);

        // PA: attn (blocks 0-7) + ple_fin l==0 (blocks 8-37) + KV copy slice (rest)
        if (bid < 8) attn_task(p, l, bid, full, smem);
        else if (bid < 38) { if (l==0) ple_fin_task(p, bid-8, smem); }
        else {
            int kw = (bid-38)*4 + wid;
            int kstep = ((int)gridDim.x - 38)*4;
            for (int k=kw; k<86; k+=kstep){
                int base = (l*86 + k)*16;
                for (int rr=0; rr<16; rr++){
                    int row = base+rr;
                    if (row < 20480){
                        const float* s; float* d;
                        if (kv_row(p, row, s, d))
                            reinterpret_cast<float4*>(d)[lane] = reinterpret_cast<const float4*>(s)[lane];
                    }
                }
            }
        }
        gridbar(p.bars);

        // PB: o-proj (1024 wave-tasks, R=16)
        for (int task=gw; task<1024; task+=NW){
            int strip=task&7, kc=task>>3, i0=kc*16;
            gemv_wave<3,16>(p.Wo + (size_t)l*2048*2048 + (size_t)i0*2048 + strip*256, 2048,
                            i0, 2048, p.ctx, nullptr, hbuf + strip*256);
        }
        gridbar(p.bars);

        // PC: gate/up (2048 wave-tasks, R=32) + ple_pre (64 wave-tasks, R=32)
        for (int task=gw; task<2112; task+=NW){
            if (task < 2048){
                int strip=task&31, kc=task>>5, i0=kc*32;
                const float* Wm = (strip<16 ? p.Wg : p.Wu) + (size_t)l*2048*4096 + (size_t)i0*4096 + (strip&15)*256;
                float* og = p.gu_all + l*8192 + (strip<16 ? 0 : 4096) + (strip&15)*256;
                gemv_wave<0,32>(Wm, 4096, i0, 2048, hbuf, p.w_post + (size_t)l*2048, og);
            } else {
                int tt=task-2048, strip=tt&7, kc=tt>>3, i0=kc*32;
                gemv_wave<2,32>(p.W_ple + (size_t)l*256*2048 + (size_t)i0*2048 + strip*256, 2048,
                                i0, 256, p.pleb + l*256, nullptr, p.pleh + l*2048 + strip*256);
            }
        }
        gridbar(p.bars);

        // PD: down-proj (1024, R=32) + ple-add (8) + patch (l==14: 9)
        {
            int npd = 1024 + 8 + (l==14 ? 9 : 0);
            for (int task=gw; task<npd; task+=NW){
                if (task < 1024){
                    int strip=task&7, kc=task>>3, i0=kc*32;
                    gemv_wave<1,32>(p.Wd + (size_t)l*4096*2048 + (size_t)i0*2048 + strip*256, 2048,
                                    i0, 4096, p.gu_all + l*8192, p.gu_all + l*8192 + 4096, hbuf + strip*256);
                } else if (task < 1032){
                    int base = (task-1024)*256 + lane*4;
                    atomicAdd(hbuf+base+0, p.pleh[l*2048+base+0]);
                    atomicAdd(hbuf+base+1, p.pleh[l*2048+base+1]);
                    atomicAdd(hbuf+base+2, p.pleh[l*2048+base+2]);
                    atomicAdd(hbuf+base+3, p.pleh[l*2048+base+3]);
                } else {
                    int tt = task-1032;
                    for (int rr=0; rr<4; rr++){
                        int i = tt*4+rr;
                        if (i < 34) patch_row(p, i, lane);
                    }
                }
            }
        }
        gridbar(p.bars);

        // PE: qkv for next layer
        if (l < 14) {
            for (int task=gw; task<1280; task+=NW) jq_task(p, l+1, hbuf, task);
            gridbar(p.bars);
        }
    }
}

extern "C" void kernel_launch(void* const* d_in, const int* in_sizes, int n_in,
                              void* d_out, int out_size, void* d_ws, size_t ws_size,
                              hipStream_t stream) {
    float* ws = (float*)d_ws;
    P p;
    p.hidden = (const float*)d_in[0];
    p.raw    = (const float*)d_in[4];
    p.cos_s  = (const float*)d_in[5];
    p.sin_s  = (const float*)d_in[6];
    p.cos_f  = (const float*)d_in[7];
    p.sin_f  = (const float*)d_in[8];
    p.Ksl    = (const float*)d_in[9];
    p.Vsl    = (const float*)d_in[10];
    p.Kfl    = (const float*)d_in[11];
    p.Vfl    = (const float*)d_in[12];
    p.ple_conv_w = (const float*)d_in[13];
    p.ple_norm_w = (const float*)d_in[14];
    p.W_ple  = (const float*)d_in[15];
    p.Wq     = (const float*)d_in[16];
    p.Wk     = (const float*)d_in[17];
    p.Wv     = (const float*)d_in[18];
    p.Wo     = (const float*)d_in[19];
    p.w_in   = (const float*)d_in[20];
    p.w_post = (const float*)d_in[21];
    p.w_qn   = (const float*)d_in[22];
    p.w_kn   = (const float*)d_in[23];
    p.Wg     = (const float*)d_in[24];
    p.Wu     = (const float*)d_in[25];
    p.Wd     = (const float*)d_in[26];
    p.out    = (float*)d_out;
    p.pleb   = p.out + O_PLE;
    p.qkv_all = ws;             // 38400
    p.gu_all  = ws + 38400;     // 122880
    p.pleh    = ws + 161280;    // 30720   (zero region = [0,192000))
    p.ctx     = ws + 192000;    // 2048
    p.proj    = ws + 194048;    // 7680
    p.kall    = ws + 201728;    // 3840
    p.vall    = ws + 205568;    // 3840
    p.bars    = (int*)(ws + 209408);

    // size the cooperative grid from the runtime's own occupancy calculator
    int maxb = 1;
    hipOccupancyMaxActiveBlocksPerMultiprocessor(&maxb, (const void*)mega, NT, 0);
    if (maxb < 1) maxb = 1;
    long long g = (long long)maxb * 256;
    int G = (g > NBMAX) ? NBMAX : (int)g;
    G &= ~7;
    if (G < 64) G = 64;

    hipMemsetAsync(ws + 209408, 0, 4608, stream);
    void* args[] = { &p };
    hipLaunchCooperativeKernel(reinterpret_cast<void*>(mega), dim3(G), dim3(NT),
                               args, 0, stream);
}

// Round 6
// 2157.900 us; speedup vs baseline: 3.9459x; 1.7326x over previous
//
#include <hip/hip_runtime.h>
#include <hip/hip_bf16.h>

#define NBMAX 512
#define NT 256
#define NL 15
#define POS 100
#define NCOL 101
#define EPS 1e-6f

// ---- output offsets (floats) ----
#define O_H    0
#define O_KS   2048
#define SZ_KS  (13*512*256)
#define O_VS   (O_KS + SZ_KS)
#define O_KF   (O_VS + SZ_KS)
#define SZ_KF  (2*1024*256)
#define O_VF   (O_KF + SZ_KF)
#define O_PLE  (O_VF + SZ_KF)
#define O_K13  (O_PLE + 30*256)
#define O_V13  (O_K13 + 512*256)
#define O_K14  (O_V13 + 512*256)
#define O_V14  (O_K14 + 1024*256)

struct P {
    const float *hidden, *raw;
    const float *cos_s, *sin_s, *cos_f, *sin_f;
    const float *Ksl, *Vsl, *Kfl, *Vfl;
    const float *ple_conv_w, *ple_norm_w, *W_ple;
    const float *Wq, *Wk, *Wv, *Wo;
    const float *w_in, *w_post, *w_qn, *w_kn;
    const float *Wg, *Wu, *Wd;
    float *out, *pleb;
    float *qkv_all, *gu_all, *pleh, *ctx, *proj, *kall, *vall;
    int *bars;
};

// coherence-point accessors (bypass non-coherent per-XCD L2)
__device__ __forceinline__ float ldc(const float* p){
    return __hip_atomic_load(p, __ATOMIC_RELAXED, __HIP_MEMORY_SCOPE_AGENT);
}
__device__ __forceinline__ void stc(float* p, float v){
    __hip_atomic_store(p, v, __ATOMIC_RELAXED, __HIP_MEMORY_SCOPE_AGENT);
}

__device__ __forceinline__ float geluf(float x) {
    float x3 = x*x*x;
    return 0.5f*x*(1.f + tanhf(0.7978845608028654f*(x + 0.044715f*x3)));
}

__device__ __forceinline__ float brsum256(float v, float* sred) {
    #pragma unroll
    for (int o=32;o>0;o>>=1) v += __shfl_xor(v,o);
    __syncthreads();
    if ((threadIdx.x&63)==0) sred[threadIdx.x>>6]=v;
    __syncthreads();
    return sred[0]+sred[1]+sred[2]+sred[3];
}
__device__ __forceinline__ float brmax256(float v, float* sred) {
    #pragma unroll
    for (int o=32;o>0;o>>=1) v = fmaxf(v,__shfl_xor(v,o));
    __syncthreads();
    if ((threadIdx.x&63)==0) sred[threadIdx.x>>6]=v;
    __syncthreads();
    return fmaxf(fmaxf(sred[0],sred[1]),fmaxf(sred[2],sred[3]));
}

// Monotonic hierarchical grid barrier: relaxed-only atomics (no wbl2/inv),
// no counter resets (no reset races). Data visibility is via coherence-point
// data ops drained by s_waitcnt before arrival.
__device__ __forceinline__ void gridbar(int* bars, int nbar) {
    __syncthreads();
    if (threadIdx.x == 0) {
        int g8 = (int)gridDim.x >> 3;
        int slot = blockIdx.x & 7;
        int* cnt    = bars + slot*32;
        int* master = bars + 8*32;
        int* gslot  = bars + (9+slot)*32;
        asm volatile("s_waitcnt vmcnt(0)" ::: "memory");
        int n = __hip_atomic_fetch_add(cnt, 1, __ATOMIC_RELAXED, __HIP_MEMORY_SCOPE_AGENT);
        if (n == nbar*g8 + (g8-1)) {
            int m = __hip_atomic_fetch_add(master, 1, __ATOMIC_RELAXED, __HIP_MEMORY_SCOPE_AGENT);
            if ((m & 7) == 7) {
                #pragma unroll
                for (int s=0;s<8;s++)
                    __hip_atomic_fetch_add(bars+(9+s)*32, 1, __ATOMIC_RELAXED, __HIP_MEMORY_SCOPE_AGENT);
            }
        }
        while (__hip_atomic_load(gslot, __ATOMIC_RELAXED, __HIP_MEMORY_SCOPE_AGENT) < nbar+1)
            __builtin_amdgcn_s_sleep(4);
    }
    __syncthreads();
}

// stage x[0..K-1] into LDS. MODE 0: rms(s0)*(1+s1); 1: gelu(s0[i])*s0[K+i];
// 2: gelu(s0); 3: raw. coh: read s0 via coherence point.
template<int MODE>
__device__ void stage_x(const float* __restrict__ s0, const float* __restrict__ s1,
                        int K, float* xs, float* sred, bool coh) {
    int t = threadIdx.x;
    if (MODE==0){
        float ss=0.f;
        for (int i=t;i<K;i+=NT){ float v = coh? ldc(s0+i):s0[i]; xs[i]=v; ss+=v*v; }
        ss = brsum256(ss,sred);
        float rs = rsqrtf(ss/(float)K+EPS);
        for (int i=t;i<K;i+=NT) xs[i] = xs[i]*rs*(1.f+s1[i]);
    } else if (MODE==1){
        for (int i=t;i<K;i+=NT){ float a=ldc(s0+i), b=ldc(s0+K+i); xs[i]=geluf(a)*b; }
    } else if (MODE==2){
        for (int i=t;i<K;i+=NT) xs[i]=geluf(ldc(s0+i));
    } else {
        for (int i=t;i<K;i+=NT) xs[i]=ldc(s0+i);
    }
    __syncthreads();
}

// one wave task: [R rows x 128 cols]; lane covers 2 cols (float2).
// Wt pre-offset to (i0,c0); xs pre-offset to i0; outc pre-offset to c0.
template<int R>
__device__ __forceinline__ void gemv_lds(const float* __restrict__ Wt, int N,
        const float* __restrict__ xs, float* __restrict__ outc) {
    int lane = threadIdx.x & 63;
    float2 acc = make_float2(0.f,0.f);
    #pragma unroll
    for (int r=0;r<R;r++){
        float x = xs[r];
        float2 w = *reinterpret_cast<const float2*>(Wt + (size_t)r*N + lane*2);
        acc.x += x*w.x; acc.y += x*w.y;
    }
    atomicAdd(outc+lane*2+0, acc.x);
    atomicAdd(outc+lane*2+1, acc.y);
}

// qkv tasks: 2560 total. xs = staged rms-x (K=2048).
__device__ void jq_task(const P& p, int l, const float* xs, int task) {
    float* qkv = p.qkv_all + l*2560;
    if (task < 2048) {
        int strip=task&15, kc=task>>4, i0=kc*16;
        gemv_lds<16>(p.Wq + (size_t)l*2048*2048 + (size_t)i0*2048 + strip*128, 2048,
                     xs+i0, qkv + strip*128);
    } else if (task < 2304) {
        int tt=task-2048, strip=tt&1, kc=tt>>1, i0=kc*16;
        gemv_lds<16>(p.Wk + (size_t)l*2048*256 + (size_t)i0*256 + strip*128, 256,
                     xs+i0, qkv + 2048 + strip*128);
    } else {
        int tt=task-2304, strip=tt&1, kc=tt>>1, i0=kc*16;
        gemv_lds<16>(p.Wv + (size_t)l*2048*256 + (size_t)i0*256 + strip*128, 256,
                     xs+i0, qkv + 2304 + strip*128);
    }
}

__device__ void ple_fin_task(const P& p, int g, float* sred) {
    int t = threadIdx.x;
    float v = ldc(p.proj + g*256+t);
    float ss = brsum256(v*v, sred);
    float rms = rsqrtf(ss*(1.f/256.f) + EPS);
    stc(p.pleb + g*256+t, (v*rms*p.ple_norm_w[t] + p.raw[g*256+t]) * 0.7071067811865476f);
}

// wave-parallel attention: one block per head.
__device__ void attn_task(const P& p, int l, int head, int full, float* smem, float* sred) {
    float* qs = smem; float* ksh = smem+256; float* vsh = smem+512;
    float* scb = smem+768; float* partial = smem+896; // 1024
    int t = threadIdx.x, wid = t>>6, lane = t&63;
    const float* qkv = p.qkv_all + l*2560;
    const float* cosv = full ? p.cos_f : p.cos_s;
    const float* sinv = full ? p.sin_f : p.sin_s;
    int fi = (l==14) ? 1 : 0;
    int si = l - (l>4 ? 1 : 0);
    const float* Kin = full ? p.Kfl + (size_t)fi*1024*256 : p.Ksl + (size_t)si*512*256;
    const float* Vin = full ? p.Vfl + (size_t)fi*1024*256 : p.Vsl + (size_t)si*512*256;
    const float* wqn = p.w_qn + l*256; const float* wkn = p.w_kn + l*256;

    float qv = ldc(qkv + head*256+t);
    float ss = brsum256(qv*qv, sred);
    float qn = qv * rsqrtf(ss*(1.f/256.f)+EPS) * (1.f+wqn[t]);
    qs[t]=qn; __syncthreads();
    float qr = qn*cosv[t] + ((t<128)? -qs[t+128] : qs[t-128])*sinv[t];
    __syncthreads(); qs[t]=qr;
    float kv = ldc(qkv + 2048+t);
    float ks2 = brsum256(kv*kv, sred);
    float kn = kv*rsqrtf(ks2*(1.f/256.f)+EPS)*(1.f+wkn[t]);
    ksh[t]=kn; __syncthreads();
    float kr = kn*cosv[t] + ((t<128)? -ksh[t+128] : ksh[t-128])*sinv[t];
    float vr = ldc(qkv + 2304+t);
    __syncthreads(); ksh[t]=kr; vsh[t]=vr;
    if (head==0){ stc(p.kall+l*256+t, kr); stc(p.vall+l*256+t, vr); }
    __syncthreads();

    // QK^T: cols distributed over 4 waves
    float4 q4 = *reinterpret_cast<const float4*>(qs + lane*4);
    for (int c=wid; c<NCOL; c+=4){
        float4 k4 = (c==POS) ? *reinterpret_cast<const float4*>(ksh + lane*4)
                             : *reinterpret_cast<const float4*>(Kin + (size_t)c*256 + lane*4);
        float d = q4.x*k4.x + q4.y*k4.y + q4.z*k4.z + q4.w*k4.w;
        #pragma unroll
        for (int o=32;o>0;o>>=1) d += __shfl_xor(d,o);
        if (lane==0) scb[c] = d * 0.0625f;
    }
    __syncthreads();
    float score = (t<NCOL) ? scb[t] : -1e30f;
    float mx = brmax256(score, sred);
    float e = (t<NCOL) ? expf(score-mx) : 0.f;
    float s = brsum256(e, sred);
    if (t<128) scb[t] = (t<NCOL) ? e/s : 0.f;
    __syncthreads();

    // PV: each wave covers all 256 dims (lane*4), cols c = wid mod 4
    float4 a4 = make_float4(0.f,0.f,0.f,0.f);
    for (int c=wid; c<NCOL; c+=4){
        float sc = scb[c];
        float4 v4 = (c==POS) ? *reinterpret_cast<const float4*>(vsh + lane*4)
                             : *reinterpret_cast<const float4*>(Vin + (size_t)c*256 + lane*4);
        a4.x += sc*v4.x; a4.y += sc*v4.y; a4.z += sc*v4.z; a4.w += sc*v4.w;
    }
    *reinterpret_cast<float4*>(partial + wid*256 + lane*4) = a4;
    __syncthreads();
    float o = partial[t] + partial[256+t] + partial[512+t] + partial[768+t];
    stc(p.ctx + head*256+t, o);
}

__device__ bool kv_row(const P& p, int row, const float*& src, float*& dst) {
    if (row < 6656) {
        int r = row&511; dst = p.out + O_KS + (size_t)row*256;
        if (r==POS) return false; src = p.Ksl + (size_t)row*256;
    } else if (row < 13312) {
        int idx = row-6656; int r = idx&511; dst = p.out + O_VS + (size_t)idx*256;
        if (r==POS) return false; src = p.Vsl + (size_t)idx*256;
    } else if (row < 15360) {
        int idx = row-13312; int r = idx&1023; dst = p.out + O_KF + (size_t)idx*256;
        if (r==POS) return false; src = p.Kfl + (size_t)idx*256;
    } else if (row < 17408) {
        int idx = row-15360; int r = idx&1023; dst = p.out + O_VF + (size_t)idx*256;
        if (r==POS) return false; src = p.Vfl + (size_t)idx*256;
    } else if (row < 17920) {
        int r = row-17408; dst = p.out + O_K13 + (size_t)r*256;
        if (r==POS) return false; src = p.Ksl + (size_t)(12*512+r)*256;
    } else if (row < 18432) {
        int r = row-17920; dst = p.out + O_V13 + (size_t)r*256;
        if (r==POS) return false; src = p.Vsl + (size_t)(12*512+r)*256;
    } else if (row < 19456) {
        int r = row-18432; dst = p.out + O_K14 + (size_t)r*256;
        if (r==POS) return false; src = p.Kfl + (size_t)(1024+r)*256;
    } else {
        int r = row-19456; dst = p.out + O_V14 + (size_t)r*256;
        if (r==POS) return false; src = p.Vfl + (size_t)(1024+r)*256;
    }
    return true;
}

__device__ __forceinline__ int slay(int s) { return s + (s>=4 ? 1 : 0); }

__device__ void patch_row(const P& p, int i, int lane) {
    const float* src; float* dst;
    if (i < 13)      { dst = p.out + O_KS + ((size_t)i*512+POS)*256;        src = p.kall + slay(i)*256; }
    else if (i < 26) { int s=i-13; dst = p.out + O_VS + ((size_t)s*512+POS)*256; src = p.vall + slay(s)*256; }
    else if (i==26)  { dst = p.out + O_KF + (size_t)POS*256;                src = p.kall + 4*256; }
    else if (i==27)  { dst = p.out + O_KF + (size_t)(1024+POS)*256;         src = p.kall + 14*256; }
    else if (i==28)  { dst = p.out + O_VF + (size_t)POS*256;                src = p.vall + 4*256; }
    else if (i==29)  { dst = p.out + O_VF + (size_t)(1024+POS)*256;         src = p.vall + 14*256; }
    else if (i==30)  { dst = p.out + O_K13 + (size_t)POS*256;               src = p.kall + 13*256; }
    else if (i==31)  { dst = p.out + O_V13 + (size_t)POS*256;               src = p.vall + 13*256; }
    else if (i==32)  { dst = p.out + O_K14 + (size_t)POS*256;               src = p.kall + 14*256; }
    else             { dst = p.out + O_V14 + (size_t)POS*256;               src = p.vall + 14*256; }
    #pragma unroll
    for (int j=0;j<4;j++) dst[lane*4+j] = ldc(src + lane*4+j);
}

__global__ __launch_bounds__(NT, 4) void mega(P p) {
    __shared__ float smem[4360];
    float* sred = smem + 4352;
    int bid = blockIdx.x, t = threadIdx.x;
    int wid = t>>6, lane = t&63;
    int gw = bid*4 + wid;
    int NW = (int)gridDim.x * 4;
    float* hbuf = p.out + O_H;
    int nb = 0;

    // Pz: zero accumulators (192000 floats at coherence point), copy h
    for (int i=bid*NT+t; i<192000; i+=(int)gridDim.x*NT) stc(p.qkv_all+i, 0.f);
    if (bid==0) for (int i=t;i<2048;i+=NT) stc(hbuf+i, p.hidden[i]);
    gridbar(p.bars, nb++);

    // P0: qkv(layer0 from hidden) 2560 + ple_conv 1920 tasks
    stage_x<0>(p.hidden, p.w_in, 2048, smem, sred, false);
    for (int task=gw; task<4480; task+=NW){
        if (task<2560) jq_task(p, 0, smem, task);
        else {
            int t4 = (task-2560)*4;
            for (int rr=0; rr<4; rr++){
                int row = t4+rr;
                const float4* wr = reinterpret_cast<const float4*>(p.ple_conv_w + (size_t)row*2048);
                const float4* hr = reinterpret_cast<const float4*>(p.hidden);
                float acc = 0.f;
                #pragma unroll
                for (int it=0; it<8; it++){
                    int idx = it*64+lane;
                    float4 w = wr[idx], x = hr[idx];
                    acc += w.x*x.x + w.y*x.y + w.z*x.z + w.w*x.w;
                }
                #pragma unroll
                for (int o=32;o>0;o>>=1) acc += __shfl_xor(acc,o);
                if (lane==0) stc(p.proj+row, acc * 0.022097086912079608f);
            }
        }
    }
    gridbar(p.bars, nb++);

    for (int l=0; l<NL; l++) {
        int full = (l==4 || l==14);

        // PA: attn (blocks 0-7) + ple_fin l==0 (8-37) + KV copy slice (rest)
        if (bid < 8) attn_task(p, l, bid, full, smem, sred);
        else if (bid < 38) { if (l==0) ple_fin_task(p, bid-8, sred); }
        else {
            int kw = (bid-38)*4 + wid;
            int kstep = ((int)gridDim.x - 38)*4;
            for (int k=kw; k<86; k+=kstep){
                int base = (l*86 + k)*16;
                for (int rr=0; rr<16; rr++){
                    int row = base+rr;
                    if (row < 20480){
                        const float* s; float* d;
                        if (kv_row(p, row, s, d))
                            reinterpret_cast<float4*>(d)[lane] = reinterpret_cast<const float4*>(s)[lane];
                    }
                }
            }
        }
        gridbar(p.bars, nb++);

        // PB: o-proj, 2048 tasks (16 strips x 128 kchunks, R=16)
        stage_x<3>(p.ctx, nullptr, 2048, smem, sred, true);
        for (int task=gw; task<2048; task+=NW){
            int strip=task&15, kc=task>>4, i0=kc*16;
            gemv_lds<16>(p.Wo + (size_t)l*2048*2048 + (size_t)i0*2048 + strip*128, 2048,
                         smem+i0, hbuf + strip*128);
        }
        gridbar(p.bars, nb++);

        // PC: gate(2048) + up(2048) + ple_pre(128) tasks
        stage_x<0>(hbuf, p.w_post + (size_t)l*2048, 2048, smem, sred, true);
        stage_x<2>(p.pleb + l*256, nullptr, 256, smem+2048, sred, true);
        for (int task=gw; task<4224; task+=NW){
            if (task < 4096){
                int half = task>>11;          // 0=gate, 1=up
                int tt = task & 2047;
                int strip=tt&31, kc=tt>>5, i0=kc*32;
                const float* Wm = (half? p.Wu : p.Wg) + (size_t)l*2048*4096 + (size_t)i0*4096 + strip*128;
                float* og = p.gu_all + l*8192 + half*4096 + strip*128;
                gemv_lds<32>(Wm, 4096, smem+i0, og);
            } else {
                int tt=task-4096, strip=tt&15, kc=tt>>4, i0=kc*32;
                gemv_lds<32>(p.W_ple + (size_t)l*256*2048 + (size_t)i0*2048 + strip*128, 2048,
                             smem+2048+i0, p.pleh + l*2048 + strip*128);
            }
        }
        gridbar(p.bars, nb++);

        // PD: down-proj (2048, R=32) + ple-add (8) + patch (l==14: 9)
        stage_x<1>(p.gu_all + l*8192, nullptr, 4096, smem, sred, true);
        {
            int npd = 2048 + 8 + (l==14 ? 9 : 0);
            for (int task=gw; task<npd; task+=NW){
                if (task < 2048){
                    int strip=task&15, kc=task>>4, i0=kc*32;
                    gemv_lds<32>(p.Wd + (size_t)l*4096*2048 + (size_t)i0*2048 + strip*128, 2048,
                                 smem+i0, hbuf + strip*128);
                } else if (task < 2056){
                    int base = (task-2048)*256 + lane*4;
                    #pragma unroll
                    for (int j=0;j<4;j++) atomicAdd(hbuf+base+j, ldc(p.pleh + l*2048+base+j));
                } else {
                    int tt = task-2056;
                    for (int rr=0; rr<4; rr++){
                        int i = tt*4+rr;
                        if (i < 34) patch_row(p, i, lane);
                    }
                }
            }
        }
        gridbar(p.bars, nb++);

        // PE: qkv for next layer
        if (l < 14) {
            stage_x<0>(hbuf, p.w_in + (size_t)(l+1)*2048, 2048, smem, sred, true);
            for (int task=gw; task<2560; task+=NW) jq_task(p, l+1, smem, task);
            gridbar(p.bars, nb++);
        }
    }
}

extern "C" void kernel_launch(void* const* d_in, const int* in_sizes, int n_in,
                              void* d_out, int out_size, void* d_ws, size_t ws_size,
                              hipStream_t stream) {
    float* ws = (float*)d_ws;
    P p;
    p.hidden = (const float*)d_in[0];
    p.raw    = (const float*)d_in[4];
    p.cos_s  = (const float*)d_in[5];
    p.sin_s  = (const float*)d_in[6];
    p.cos_f  = (const float*)d_in[7];
    p.sin_f  = (const float*)d_in[8];
    p.Ksl    = (const float*)d_in[9];
    p.Vsl    = (const float*)d_in[10];
    p.Kfl    = (const float*)d_in[11];
    p.Vfl    = (const float*)d_in[12];
    p.ple_conv_w = (const float*)d_in[13];
    p.ple_norm_w = (const float*)d_in[14];
    p.W_ple  = (const float*)d_in[15];
    p.Wq     = (const float*)d_in[16];
    p.Wk     = (const float*)d_in[17];
    p.Wv     = (const float*)d_in[18];
    p.Wo     = (const float*)d_in[19];
    p.w_in   = (const float*)d_in[20];
    p.w_post = (const float*)d_in[21];
    p.w_qn   = (const float*)d_in[22];
    p.w_kn   = (const float*)d_in[23];
    p.Wg     = (const float*)d_in[24];
    p.Wu     = (const float*)d_in[25];
    p.Wd     = (const float*)d_in[26];
    p.out    = (float*)d_out;
    p.pleb   = p.out + O_PLE;
    p.qkv_all = ws;             // 38400
    p.gu_all  = ws + 38400;     // 122880
    p.pleh    = ws + 161280;    // 30720   (zero region = [0,192000))
    p.ctx     = ws + 192000;    // 2048
    p.proj    = ws + 194048;    // 7680
    p.kall    = ws + 201728;    // 3840
    p.vall    = ws + 205568;    // 3840
    p.bars    = (int*)(ws + 209408);

    int maxb = 1;
    hipOccupancyMaxActiveBlocksPerMultiprocessor(&maxb, (const void*)mega, NT, 0);
    if (maxb < 1) maxb = 1;
    long long g = (long long)maxb * 256;
    int G = (g > NBMAX) ? NBMAX : (int)g;
    G &= ~7;
    if (G < 64) G = 64;

    hipMemsetAsync(ws + 209408, 0, 4608, stream);
    void* args[] = { &p };
    hipLaunchCooperativeKernel(reinterpret_cast<void*>(mega), dim3(G), dim3(NT),
                               args, 0, stream);
}